// Round 9
// baseline (423.370 us; speedup 1.0000x reference)
//
#include <hip/hip_runtime.h>

// LSTM B=2048, T=512, I=1, H=64, O=1 (PyTorch gate order i,f,g,o).
// v8: TWO ANTI-PHASED CHAINS PER WG (ILP instead of TLP):
//   WG = 512 thr (8 waves) owns 8 batches = chain A (b 0-3) + chain B (b 4-7);
//   grid = 256 -> 1 WG/CU, 2 waves/SIMD, NO redundant MFMA (v7's mistake).
//   Interval 1: MFMA-B(t) on all 8 waves (each wave owns 32 gates = 2 N-tiles,
//               4 MFMAs) || act-A(t) on waves 4-7.   barrier.
//   Interval 2: MFMA-A(t+1) || act-B(t) on waves 0-3. barrier.
//   Two independent dep-chains per interval -> ds_read/MFMA latency of one
//   chain hides under the other's transcendental chain. Wave->SIMD round
//   robin pairs one act-wave + one mfma-only wave per SIMD per interval.
// Proven pieces from v4: fp16 single-product MFMA (fp32 acc), bias+x*w_ih in
//   C-init, XOR-swizzled fp16 h A-frags, linear conflict-free g_raw exchange,
//   pre-scaled gates (-log2e / -2log2e) so act = rcp(1+exp2(g)).

typedef float    f32x4 __attribute__((ext_vector_type(4)));
typedef _Float16 f16x8 __attribute__((ext_vector_type(8)));

namespace {
constexpr int Bsz = 2048;
constexpr int Tsz = 512;
constexpr int NBW = 8;    // batches per WG (two 4-batch chains)
}

__device__ __forceinline__ float rcp_f(float v)  { return __builtin_amdgcn_rcpf(v); }
__device__ __forceinline__ float exp2_f(float v) { return __builtin_amdgcn_exp2f(v); }

// gs = -log2e * gate -> sigmoid(gate); saturates at +-inf
__device__ __forceinline__ float sigm_s(float gs)  { return rcp_f(1.0f + exp2_f(gs)); }
// gs = -2log2e * gate -> tanh(gate)
__device__ __forceinline__ float tanh_s(float gs)  { return fmaf(2.0f, rcp_f(1.0f + exp2_f(gs)), -1.0f); }
// plain tanh for cell state
__device__ __forceinline__ float tanh_plain(float v) {
    return fmaf(2.0f, rcp_f(1.0f + exp2_f(v * -2.88539008178f)), -1.0f);
}

__global__ __launch_bounds__(512, 2)
void lstm_v8(const float* __restrict__ x,      // [B,T]
             const float* __restrict__ w_ih,   // [256]
             const float* __restrict__ w_hh,   // [256,64]
             const float* __restrict__ b_ih,   // [256]
             const float* __restrict__ b_hh,   // [256]
             const float* __restrict__ w_lin,  // [64]
             const float* __restrict__ b_lin,  // [1]
             float* __restrict__ out)          // [B]
{
    __shared__ __align__(16) float x_lds[Tsz][NBW];     // 16 KB, [t][b]
    __shared__ __align__(16) char  hA[2][16 * 128];     // 2x2 KB fp16 A-frag (rows 4..15 = 0)
    __shared__ __align__(16) float g_raw[2][256 * 4];   // 2x4 KB, [gate][batch]
    __shared__ float part[32];

    const int tid = threadIdx.x;
    const int wv  = tid >> 6;          // 0..7
    const int ln  = tid & 63;
    const int col = ln & 15;
    const int grp = ln >> 4;
    const int b0  = blockIdx.x * NBW;

    constexpr float LOG2E = 1.44269504089f;
    const int   gtype = wv >> 1;                               // 0..3 = i,f,g,o
    const float s     = (gtype == 2) ? (-2.0f * LOG2E) : (-LOG2E);

    // ---- stage x[b0..b0+7][:] transposed into LDS: x_lds[t][b] ----
    #pragma unroll
    for (int it = 0; it < 2; ++it) {
        const int i  = tid + it * 512;           // 0..1023
        const int b  = i >> 7;                   // 128 float4 per batch row
        const int t4 = i & 127;
        const float4 v = ((const float4*)(x + (size_t)(b0 + b) * Tsz))[t4];
        x_lds[t4 * 4 + 0][b] = v.x;
        x_lds[t4 * 4 + 1][b] = v.y;
        x_lds[t4 * 4 + 2][b] = v.z;
        x_lds[t4 * 4 + 3][b] = v.w;
    }

    // ---- W B-operand frags (one-time): wave wv owns gates [32wv, 32wv+32)
    //      = 2 N-tiles; k = kc*32 + grp*8 + e; pre-scaled by s ----
    f16x8 Wf[2][2];
    float wihc[2], biasc[2];
    #pragma unroll
    for (int tn = 0; tn < 2; ++tn) {
        const int gate = wv * 32 + tn * 16 + col;
        const float* wrow = w_hh + (size_t)gate * 64;
        #pragma unroll
        for (int kc = 0; kc < 2; ++kc) {
            f16x8 w;
            #pragma unroll
            for (int e = 0; e < 8; ++e)
                w[e] = (_Float16)(wrow[kc * 32 + grp * 8 + e] * s);
            Wf[tn][kc] = w;
        }
        wihc[tn]  = w_ih[gate] * s;
        biasc[tn] = (b_ih[gate] + b_hh[gate]) * s;
    }

    // ---- A-frag (h) read offsets: row = col (batch), k = kc*32 + grp*8 + e ----
    const int sw    = (col & 7) << 4;
    const int aoff0 = col * 128 + ((grp * 16) ^ sw);
    const int aoff1 = col * 128 + ((64 + grp * 16) ^ sw);

    // ---- act ownership: waves 4-7 -> chain 0 (batches 0-3),
    //                     waves 0-3 -> chain 1 (batches 4-7) ----
    const int myChain = (wv >= 4) ? 0 : 1;
    const int idx = tid & 255;          // = pj*4 + pb within the chain's half
    const int pb  = idx & 3;
    const int pj  = idx >> 2;           // 0..63
    const float wlin  = w_lin[pj];
    const int   hwoff = pb * 128 + ((2 * pj) ^ (pb << 4));

    // zero both hA buffers (rows 4..15 must stay 0; rows 0..3 = h0 = 0)
    ((float2*)hA)[tid] = make_float2(0.0f, 0.0f);    // 512 x 8B = 4 KB

    float c = 0.0f, h = 0.0f;

#define MFMA_STEP(ch, tt)                                                      \
    {                                                                          \
        const float4 xb = *(const float4*)&x_lds[(tt)][(ch) * 4];              \
        const f16x8 A0 = *(const f16x8*)(hA[(ch)] + aoff0);                    \
        const f16x8 A1 = *(const f16x8*)(hA[(ch)] + aoff1);                    \
        f32x4 a0, a1;                                                          \
        a0[0] = fmaf(xb.x, wihc[0], biasc[0]);                                 \
        a0[1] = fmaf(xb.y, wihc[0], biasc[0]);                                 \
        a0[2] = fmaf(xb.z, wihc[0], biasc[0]);                                 \
        a0[3] = fmaf(xb.w, wihc[0], biasc[0]);                                 \
        a1[0] = fmaf(xb.x, wihc[1], biasc[1]);                                 \
        a1[1] = fmaf(xb.y, wihc[1], biasc[1]);                                 \
        a1[2] = fmaf(xb.z, wihc[1], biasc[1]);                                 \
        a1[3] = fmaf(xb.w, wihc[1], biasc[1]);                                 \
        a0 = __builtin_amdgcn_mfma_f32_16x16x32_f16(A0, Wf[0][0], a0, 0, 0, 0);\
        a0 = __builtin_amdgcn_mfma_f32_16x16x32_f16(A1, Wf[0][1], a0, 0, 0, 0);\
        a1 = __builtin_amdgcn_mfma_f32_16x16x32_f16(A0, Wf[1][0], a1, 0, 0, 0);\
        a1 = __builtin_amdgcn_mfma_f32_16x16x32_f16(A1, Wf[1][1], a1, 0, 0, 0);\
        if (ln < 16) {                                                         \
            *(f32x4*)&g_raw[(ch)][(wv * 32 + ln) * 4]      = a0;               \
            *(f32x4*)&g_raw[(ch)][(wv * 32 + 16 + ln) * 4] = a1;               \
        }                                                                      \
    }

#define ACT_STEP(ch)                                                           \
    if (myChain == (ch)) {                                                     \
        const float gi = g_raw[(ch)][idx +   0];                               \
        const float gf = g_raw[(ch)][idx + 256];                               \
        const float gg = g_raw[(ch)][idx + 512];                               \
        const float go = g_raw[(ch)][idx + 768];                               \
        const float ig = sigm_s(gi);                                           \
        const float fg = sigm_s(gf);                                           \
        const float tg = tanh_s(gg);                                           \
        const float og = sigm_s(go);                                           \
        c = fmaf(fg, c, ig * tg);                                              \
        h = og * tanh_plain(c);                                                \
        *(_Float16*)(hA[(ch)] + hwoff) = (_Float16)h;                          \
    }

    __syncthreads();

    MFMA_STEP(0, 0)          // chain A gates(t=0) from h=0
    __syncthreads();

    for (int k = 0; k < Tsz; ++k) {
        // interval 1: MFMA-B(k) || act-A(k)
        MFMA_STEP(1, k)
        ACT_STEP(0)
        __syncthreads();
        // interval 2: MFMA-A(k+1) || act-B(k)   (k=511: wasted MFMA, harmless)
        const int kn = (k + 1) & (Tsz - 1);
        MFMA_STEP(0, kn)
        ACT_STEP(1)
        __syncthreads();
    }

#undef MFMA_STEP
#undef ACT_STEP

    // ---- out[b0+b] = sum_j h[b][j]*w_lin[j] + b_lin ----
    // lane = (pj&15)*4 + pb within wave: reduce over pj bits (offsets 4..32)
    float p = h * wlin;
    #pragma unroll
    for (int off = 4; off < 64; off <<= 1)
        p += __shfl_xor(p, off, 64);
    if (ln < 4) part[wv * 4 + ln] = p;   // partial for pb=ln over wave's 16 pj
    __syncthreads();
    if (tid < NBW) {
        // batch tid: chain 0 (b 0-3) partials on waves 4-7; chain 1 on waves 0-3
        const int wbase = (tid < 4) ? 4 : 0;
        out[b0 + tid] = part[(wbase + 0) * 4 + (tid & 3)] +
                        part[(wbase + 1) * 4 + (tid & 3)] +
                        part[(wbase + 2) * 4 + (tid & 3)] +
                        part[(wbase + 3) * 4 + (tid & 3)] + b_lin[0];
    }
}

extern "C" void kernel_launch(void* const* d_in, const int* in_sizes, int n_in,
                              void* d_out, int out_size, void* d_ws, size_t ws_size,
                              hipStream_t stream) {
    const float* x     = (const float*)d_in[0];
    const float* w_ih  = (const float*)d_in[1];
    const float* w_hh  = (const float*)d_in[2];
    const float* b_ih  = (const float*)d_in[3];
    const float* b_hh  = (const float*)d_in[4];
    const float* w_lin = (const float*)d_in[5];
    const float* b_lin = (const float*)d_in[6];
    float* out = (float*)d_out;

    dim3 grid(Bsz / NBW);   // 256 -> 1 WG/CU
    dim3 block(512);
    lstm_v8<<<grid, block, 0, stream>>>(x, w_ih, w_hh, b_ih, b_hh,
                                        w_lin, b_lin, out);
}